// Round 1
// baseline (228.860 us; speedup 1.0000x reference)
//
#include <hip/hip_runtime.h>

// Problem constants (from reference):
//   N = 128 rows, C = 1000 classes, conf table 50000 x 1000 fp32.
// Identity: sum_k |p[n,k] - I[j,k]| = 2 - 2*p[n,j]  (softmax row sums to 1).
// => out = mean_n( 2*sum_j conf[idx[n],j] - 2*(sum_j e^{o-m} conf)/Z )

#define NROWS 128
#define NCLS  1000

__global__ __launch_bounds__(256) void row_loss_kernel(
    const float* __restrict__ outputs,      // [NROWS, NCLS]
    const float* __restrict__ conf,         // [50000, NCLS]
    const int*   __restrict__ index,        // [NROWS]
    float* __restrict__ ws)                 // [NROWS] per-row results
{
    const int row  = blockIdx.x;
    const int tid  = threadIdx.x;
    const int lane = tid & 63;
    const int wave = tid >> 6;

    __shared__ float redm[4];
    __shared__ float rz[4], rd[4], rs[4];
    __shared__ float bmax;

    // NCLS = 1000 = 250 * 4: threads 0..249 each own one float4; 250..255 idle.
    const int j = tid * 4;
    float4 o = make_float4(-INFINITY, -INFINITY, -INFINITY, -INFINITY);
    if (j < NCLS) {
        o = *reinterpret_cast<const float4*>(outputs + (size_t)row * NCLS + j);
    }

    // ---- block max ----
    float m = fmaxf(fmaxf(o.x, o.y), fmaxf(o.z, o.w));
    #pragma unroll
    for (int off = 32; off > 0; off >>= 1)
        m = fmaxf(m, __shfl_down(m, off, 64));
    if (lane == 0) redm[wave] = m;
    __syncthreads();
    if (tid == 0)
        bmax = fmaxf(fmaxf(redm[0], redm[1]), fmaxf(redm[2], redm[3]));
    __syncthreads();
    m = bmax;

    // ---- fused pass: Z, dot = sum e*conf, sc = sum conf ----
    float z = 0.f, dot = 0.f, sc = 0.f;
    if (j < NCLS) {
        const float* crow = conf + (size_t)index[row] * NCLS;
        const float4 cf = *reinterpret_cast<const float4*>(crow + j);
        const float e0 = __expf(o.x - m);
        const float e1 = __expf(o.y - m);
        const float e2 = __expf(o.z - m);
        const float e3 = __expf(o.w - m);
        z   = (e0 + e1) + (e2 + e3);
        dot = e0 * cf.x + e1 * cf.y + e2 * cf.z + e3 * cf.w;
        sc  = (cf.x + cf.y) + (cf.z + cf.w);
    }
    #pragma unroll
    for (int off = 32; off > 0; off >>= 1) {
        z   += __shfl_down(z,   off, 64);
        dot += __shfl_down(dot, off, 64);
        sc  += __shfl_down(sc,  off, 64);
    }
    if (lane == 0) { rz[wave] = z; rd[wave] = dot; rs[wave] = sc; }
    __syncthreads();
    if (tid == 0) {
        const float Z = (rz[0] + rz[1]) + (rz[2] + rz[3]);
        const float D = (rd[0] + rd[1]) + (rd[2] + rd[3]);
        const float S = (rs[0] + rs[1]) + (rs[2] + rs[3]);
        ws[row] = 2.f * S - 2.f * D / Z;
    }
}

__global__ __launch_bounds__(128) void final_reduce_kernel(
    const float* __restrict__ ws, float* __restrict__ out)
{
    const int tid = threadIdx.x;   // 128 threads = 2 waves
    float v = ws[tid];
    #pragma unroll
    for (int off = 32; off > 0; off >>= 1)
        v += __shfl_down(v, off, 64);
    __shared__ float r[2];
    if ((tid & 63) == 0) r[tid >> 6] = v;
    __syncthreads();
    if (tid == 0) out[0] = (r[0] + r[1]) * (1.0f / (float)NROWS);
}

extern "C" void kernel_launch(void* const* d_in, const int* in_sizes, int n_in,
                              void* d_out, int out_size, void* d_ws, size_t ws_size,
                              hipStream_t stream) {
    const float* outputs = (const float*)d_in[0];  // [128, 1000]
    const float* conf    = (const float*)d_in[1];  // [50000, 1000]
    const int*   index   = (const int*)d_in[2];    // [128]
    float* out = (float*)d_out;                    // scalar
    float* ws  = (float*)d_ws;                     // >= 128 floats

    row_loss_kernel<<<NROWS, 256, 0, stream>>>(outputs, conf, index, ws);
    final_reduce_kernel<<<1, 128, 0, stream>>>(ws, out);
}